// Round 21
// baseline (194.029 us; speedup 1.0000x reference)
//
#include <hip/hip_runtime.h>
#include <math.h>

#define BB      16384   // batch rows
#define DD      128     // embedding dim
#define VV      1000000 // vocab
#define NSAMP   8192    // NUM_SAMPLED
#define NT      (NSAMP / 64)   // 128 N-tiles of 64 candidates

typedef __attribute__((ext_vector_type(8)))  unsigned short u16x8;
typedef __attribute__((ext_vector_type(8)))  __bf16         bf16x8;
typedef __attribute__((ext_vector_type(16))) float          f32x16;

__device__ __forceinline__ unsigned rotl32(unsigned x, unsigned r) {
    return (x << r) | (x >> (32u - r));
}

// RNE float -> bf16
__device__ __forceinline__ unsigned short bf16r(float v) {
    unsigned b = __builtin_bit_cast(unsigned, v);
    unsigned r = (b + 0x7fffu + ((b >> 16) & 1u)) >> 16;
    return (unsigned short)r;
}

// async 16B global -> LDS (per-lane global src, wave-uniform LDS base)
__device__ __forceinline__ void gload16(const void* g, void* l) {
    __builtin_amdgcn_global_load_lds(
        (const __attribute__((address_space(1))) unsigned*)g,
        (__attribute__((address_space(3))) unsigned*)l, 16, 0, 0);
}

// ---------------------------------------------------------------------------
// XLA:CPU vectorized f32 exp (Cephes, NO FMA — VERIFIED R10-R20).
// ---------------------------------------------------------------------------
__device__ __forceinline__ float xla_expf(float x) {
#pragma clang fp contract(off)
    float fx = floorf(x * 1.44269504088896341f + 0.5f);
    float tmp = fx * 0.693359375f;
    float z2  = fx * -2.12194440e-4f;
    float r = x - tmp;
    r = r - z2;
    float z = r * r;
    float y = 1.9875691500E-4f;
    y = y * r + 1.3981999507E-3f;
    y = y * r + 8.3334519073E-3f;
    y = y * r + 4.1665795894E-2f;
    y = y * r + 1.6666665459E-1f;
    y = y * r + 5.0000001201E-1f;
    y = y * z + r;
    y = y + 1.0f;
    int n = (int)fx;
    float p2n = __builtin_bit_cast(float, (unsigned)((n + 127) << 23));
    return y * p2n;
}

__device__ __forceinline__ float log_q32(float idf, float logr) {
    float l2 = (float)log((double)(idf + 2.0f));
    float l1 = (float)log((double)(idf + 1.0f));
    float q  = (l2 - l1) / logr;
    return (float)log((double)q);
}

// ---------------------------------------------------------------------------
// Kernel 1: prep = per-block dtype detect + tgt32 resolve + x->bf16 +
// threefry sample/corr (first 8192 threads). VERIFIED numerics; detect is
// recomputed per block (no cross-block flag race).
// ---------------------------------------------------------------------------
__global__ __launch_bounds__(256) void prep_kernel(
    const float* __restrict__ x, const int* __restrict__ tgt,
    const float* __restrict__ bias,
    unsigned short* __restrict__ Xb, int* __restrict__ tgt32,
    int* __restrict__ ids, float* __restrict__ corr,
    float logr, float logns)
{
    // ---- local dtype detect (OR of first 2048 odd words; int64 -> all 0) --
    __shared__ unsigned red[256];
    __shared__ unsigned is64s;
    {
        const unsigned* traw = (const unsigned*)tgt;
        unsigned acc = 0;
        for (int i = threadIdx.x; i < 2048; i += 256) acc |= traw[2 * i + 1];
        red[threadIdx.x] = acc;
        __syncthreads();
        for (int s = 128; s > 0; s >>= 1) {
            if ((int)threadIdx.x < s) red[threadIdx.x] |= red[threadIdx.x + s];
            __syncthreads();
        }
        if (threadIdx.x == 0) is64s = (red[0] == 0u) ? 1u : 0u;
        __syncthreads();
    }
    const unsigned is64 = is64s;

    int g = blockIdx.x * 256 + threadIdx.x;        // 0 .. 262143
    int row = g >> 4, chunk = g & 15;

    // ---- resolve target dtype -> int32 (one thread per row) ----
    if (chunk == 0) tgt32[row] = is64 ? tgt[2 * row] : tgt[row];

    // ---- x -> bf16 (thread per 8 elements) ----
    {
        const float4* src = (const float4*)(x + (size_t)row * DD + chunk * 8);
        float4 a = src[0], b = src[1];
        uint4 o;
        o.x = (unsigned)bf16r(a.x) | ((unsigned)bf16r(a.y) << 16);
        o.y = (unsigned)bf16r(a.z) | ((unsigned)bf16r(a.w) << 16);
        o.z = (unsigned)bf16r(b.x) | ((unsigned)bf16r(b.y) << 16);
        o.w = (unsigned)bf16r(b.z) | ((unsigned)bf16r(b.w) << 16);
        *(uint4*)(Xb + (size_t)row * DD + chunk * 8) = o;
    }

    // ---- sampling (first 8192 threads) ----
    if (g < NSAMP) {
        int i = g;
        const unsigned k0 = 0u, k1 = 1u;
        const unsigned k2 = 0x1BD11BDAu ^ k0 ^ k1;
        unsigned x0 = 0u + k0;
        unsigned x1 = (unsigned)i + k1;
#define TFR(r) { x0 += x1; x1 = rotl32(x1, (r)); x1 ^= x0; }
        TFR(13) TFR(15) TFR(26) TFR(6)   x0 += k1; x1 += k2 + 1u;
        TFR(17) TFR(29) TFR(16) TFR(24)  x0 += k2; x1 += k0 + 2u;
        TFR(13) TFR(15) TFR(26) TFR(6)   x0 += k0; x1 += k1 + 3u;
        TFR(17) TFR(29) TFR(16) TFR(24)  x0 += k1; x1 += k2 + 4u;
        TFR(13) TFR(15) TFR(26) TFR(6)   x0 += k2; x1 += k0 + 5u;
#undef TFR
        unsigned bits = x0 ^ x1;

        unsigned fb = (bits >> 9) | 0x3f800000u;
        float u = __builtin_bit_cast(float, fb) - 1.0f;
        float t = u * logr;
        float ef = xla_expf(t);
        int id = (int)floorf(ef) - 1;
        id = id < 0 ? 0 : (id > VV - 1 ? VV - 1 : id);

        float lp = log_q32((float)id, logr);
        ids[i]  = id;
        corr[i] = bias[id] - (logns + lp);
    }
}

// ---------------------------------------------------------------------------
// Kernel 2: gather candidate rows -> bf16 Wh (coalesced, 512 blocks).
// ---------------------------------------------------------------------------
__global__ __launch_bounds__(256) void gather_kernel(
    const float* __restrict__ emb, const int* __restrict__ ids,
    unsigned short* __restrict__ Wh)
{
    int g = blockIdx.x * 256 + threadIdx.x;    // 0 .. 131071
    int row   = g >> 4;
    int chunk = g & 15;
    const float4* src = (const float4*)(emb + (size_t)ids[row] * DD + chunk * 8);
    float4 a = src[0], b = src[1];
    uint4 o;
    o.x = (unsigned)bf16r(a.x) | ((unsigned)bf16r(a.y) << 16);
    o.y = (unsigned)bf16r(a.z) | ((unsigned)bf16r(a.w) << 16);
    o.z = (unsigned)bf16r(b.x) | ((unsigned)bf16r(b.y) << 16);
    o.w = (unsigned)bf16r(b.z) | ((unsigned)bf16r(b.w) << 16);
    *(uint4*)(Wh + (size_t)row * DD + chunk * 8) = o;
}

// ---------------------------------------------------------------------------
// Kernel 3: GEMM — R16 verified structure at 4 blocks/CU (4 waves/SIMD):
// targets moved from 32 VGPRs to wave-uniform SGPR loads (hoisted) + a
// per-lane half-select cndmask; __launch_bounds__(256,4) caps VGPR at 128;
// grid (128, 8) = 1024 blocks = exactly 4/CU. Independent blocks give the
// cross-wave MFMA∥VALU∥LDS overlap (m114) that R18/R20 reordering couldn't.
// Math bit-identical to R16 (same loads, same exp/mask/accumulate order).
// ---------------------------------------------------------------------------
__device__ __forceinline__ int swz(int row, int slot) {
    return row * 256 + ((slot ^ (row & 15)) << 4);
}

__global__ __launch_bounds__(256, 4) void gemm_kernel(
    const unsigned short* __restrict__ Xb, const int* __restrict__ tgt32,
    const unsigned short* __restrict__ Wh,
    const int* __restrict__ ids, const float* __restrict__ corr,
    float* __restrict__ ps)
{
    __shared__ char lds[32768];   // 2 bufs x 16 KB

    const int tid  = threadIdx.x;
    const int lane = tid & 63;
    const int wid  = tid >> 6;
    const int wr   = wid >> 1, wc = wid & 1;
    const int half = lane >> 5, ln31 = lane & 31;
    const int m0   = blockIdx.x * 128;
    const int ty0  = blockIdx.y * (NT / 8);    // 16 tiles per y-eighth
    const int NTB  = NT / 8;

    // ---- A fragments: two sets of 32 rows x 128 k, bf16 direct loads ----
    u16x8 ah[2][8];
    #pragma unroll
    for (int p = 0; p < 2; p++) {
        const uint4* xr = (const uint4*)(Xb + (size_t)(m0 + wr * 64 + p * 32 + ln31) * DD);
        #pragma unroll
        for (int ks = 0; ks < 8; ks++)
            ah[p][ks] = __builtin_bit_cast(u16x8, xr[ks * 2 + half]);
    }

    float ss[2][16];
    #pragma unroll
    for (int p = 0; p < 2; p++)
        #pragma unroll
        for (int i = 0; i < 16; i++) ss[p][i] = 0.f;

    // ---- staging geometry (rule #21: linear LDS dest + inverse-swz src) ----
    const int u    = lane & 15;
    const int rsub = lane >> 4;
    int srcoff[4], ldsrow[4];
    #pragma unroll
    for (int i2 = 0; i2 < 4; i2++) {
        int row = wid * 16 + i2 * 4 + rsub;
        srcoff[i2] = row * 256 + ((u ^ (row & 15)) << 4);
        ldsrow[i2] = (wid * 16 + i2 * 4) * 256;
    }
    const int brow = wc * 32 + ln31;
    const int tb0  = m0 + wr * 64;    // uniform target base (+p*32+rowoff)

    // ---- prologue: DMA tile ty0 into buf 0 ----
    {
        const char* tb = (const char*)Wh + (size_t)(ty0 * 64) * 256;
        #pragma unroll
        for (int i2 = 0; i2 < 4; i2++)
            gload16(tb + srcoff[i2], lds + ldsrow[i2]);
    }
    __syncthreads();

    for (int t = 0; t < NTB; t++) {
        const int c = t & 1;
        if (t + 1 < NTB) {
            const char* tb = (const char*)Wh + (size_t)((ty0 + t + 1) * 64) * 256;
            char* db = lds + (c ^ 1) * 16384;
            #pragma unroll
            for (int i2 = 0; i2 < 4; i2++)
                gload16(tb + srcoff[i2], db + ldsrow[i2]);
        }

        const char* bh_base = lds + c * 16384;
        f32x16 h0, h1;
        #pragma unroll
        for (int q = 0; q < 16; q++) { h0[q] = 0.f; h1[q] = 0.f; }

        #pragma unroll
        for (int ks = 0; ks < 8; ks++) {
            int off = swz(brow, ks * 2 + half);
            bf16x8 bh = __builtin_bit_cast(bf16x8, *(const uint4*)(bh_base + off));
            bf16x8 a0 = __builtin_bit_cast(bf16x8, ah[0][ks]);
            bf16x8 a1 = __builtin_bit_cast(bf16x8, ah[1][ks]);
            h0 = __builtin_amdgcn_mfma_f32_32x32x16_bf16(a0, bh, h0, 0, 0, 0);
            h1 = __builtin_amdgcn_mfma_f32_32x32x16_bf16(a1, bh, h1, 0, 0, 0);
        }

        // epilogue: logit = C + corr - 60; exact hit mask via SGPR-resident
        // targets + per-lane half select; accumulate exp (bit-identical math)
        const int j = (ty0 + t) * 64 + wc * 32 + ln31;
        const float cc = corr[j] - 60.0f;
        const int idj = ids[j];
        #pragma unroll
        for (int i = 0; i < 16; i++) {
            const int ro = (i & 3) + 8 * (i >> 2);      // uniform row offset
            int tA0 = tgt32[tb0 + ro];                  // uniform -> SGPR
            int tA1 = tgt32[tb0 + ro + 4];
            int tB0 = tgt32[tb0 + 32 + ro];
            int tB1 = tgt32[tb0 + 32 + ro + 4];
            int ttA = half ? tA1 : tA0;                 // per-lane select
            int ttB = half ? tB1 : tB0;
            float l0 = h0[i] + cc;
            float l1 = h1[i] + cc;
            ss[0][i] += (idj == ttA) ? 0.0f : __expf(l0);
            ss[1][i] += (idj == ttB) ? 0.0f : __expf(l1);
        }

        __syncthreads();
    }

    // ---- per-row reduce over 32 col-lanes, write per-wave partial ----
    #pragma unroll
    for (int p = 0; p < 2; p++)
        #pragma unroll
        for (int i = 0; i < 16; i++) {
            float v = ss[p][i];
            v += __shfl_xor(v, 1);
            v += __shfl_xor(v, 2);
            v += __shfl_xor(v, 4);
            v += __shfl_xor(v, 8);
            v += __shfl_xor(v, 16);
            if (ln31 == 0) {
                int grow = m0 + wr * 64 + p * 32 + (i & 3) + 8 * (i >> 2) + 4 * half;
                ps[(size_t)grow * 16 + blockIdx.y * 2 + wc] = v;
            }
        }
}

// ---------------------------------------------------------------------------
// Kernel 4: finish = true logit (16 lanes/row, coalesced) + LSE combine.
// ---------------------------------------------------------------------------
__global__ __launch_bounds__(256) void finish_kernel(
    const float* __restrict__ x, const int* __restrict__ tgt32,
    const float* __restrict__ emb, const float* __restrict__ bias,
    const float* __restrict__ ps,
    float* __restrict__ out, float logr, float logns)
{
    const int gid = blockIdx.x * 256 + threadIdx.x;
    const int r   = gid >> 4;            // row
    const int l   = gid & 15;            // lane-in-row
    if (r >= BB) return;

    const int t = tgt32[r];

    const float4* xr = (const float4*)(x + (size_t)r * DD);
    const float4* wr = (const float4*)(emb + (size_t)t * DD);
    float4 xa = xr[l], xb = xr[l + 16];
    float4 wa = wr[l], wb = wr[l + 16];
    float d = xa.x*wa.x + xa.y*wa.y + xa.z*wa.z + xa.w*wa.w
            + xb.x*wb.x + xb.y*wb.y + xb.z*wb.z + xb.w*wb.w;
    d += __shfl_xor(d, 1);
    d += __shfl_xor(d, 2);
    d += __shfl_xor(d, 4);
    d += __shfl_xor(d, 8);

    if (l == 0) {
        float lp = log_q32((float)t, logr);
        float tl = d + bias[t] - (logns + lp);
        const float* p = ps + (size_t)r * 16;
        float S = 0.f;
        #pragma unroll
        for (int k = 0; k < 16; k++) S += p[k];
        out[r] = logf(expf(tl - 60.0f) + S) + 60.0f - tl;
    }
}

// ---------------------------------------------------------------------------
extern "C" void kernel_launch(void* const* d_in, const int* in_sizes, int n_in,
                              void* d_out, int out_size, void* d_ws, size_t ws_size,
                              hipStream_t stream)
{
    const float* x    = (const float*)d_in[0];
    const int*   tgt  = (const int*)d_in[1];
    const float* emb  = (const float*)d_in[2];
    const float* bias = (const float*)d_in[3];
    float* out = (float*)d_out;

    char* w = (char*)d_ws;
    int*            ids   = (int*)(w + 0);                     //  32 KB
    float*          corr  = (float*)(w + 32768);               //  32 KB
    int*            tgt32 = (int*)(w + 65536);                 //  64 KB
    unsigned short* Xb    = (unsigned short*)(w + 131072);     //   4 MB
    unsigned short* Wh    = (unsigned short*)(w + 131072 + 4194304);  // 2 MB
    float*          ps    = (float*)(w + 131072 + 4194304 + 2097152); // 1 MB

    const float logr  = (float)log(1000001.0);
    const float logns = (float)log(8192.0);

    prep_kernel<<<dim3(BB * 16 / 256), dim3(256), 0, stream>>>(
        x, tgt, bias, Xb, tgt32, ids, corr, logr, logns);
    gather_kernel<<<dim3(NSAMP * 16 / 256), dim3(256), 0, stream>>>(
        emb, ids, Wh);
    gemm_kernel<<<dim3(BB / 128, 8), dim3(256), 0, stream>>>(
        Xb, tgt32, Wh, ids, corr, ps);
    finish_kernel<<<dim3(BB * 16 / 256), dim3(256), 0, stream>>>(
        x, tgt32, emb, bias, ps, out, logr, logns);
}

// Round 22
// 76.368 us; speedup vs baseline: 2.5407x; 2.5407x over previous
//
#include <hip/hip_runtime.h>
#include <math.h>

#define BB      16384   // batch rows
#define DD      128     // embedding dim
#define VV      1000000 // vocab
#define NSAMP   8192    // NUM_SAMPLED
#define NT      (NSAMP / 64)   // 128 N-tiles of 64 candidates

typedef __attribute__((ext_vector_type(8)))  unsigned short u16x8;
typedef __attribute__((ext_vector_type(8)))  __bf16         bf16x8;
typedef __attribute__((ext_vector_type(16))) float          f32x16;

__device__ __forceinline__ unsigned rotl32(unsigned x, unsigned r) {
    return (x << r) | (x >> (32u - r));
}

// RNE float -> bf16
__device__ __forceinline__ unsigned short bf16r(float v) {
    unsigned b = __builtin_bit_cast(unsigned, v);
    unsigned r = (b + 0x7fffu + ((b >> 16) & 1u)) >> 16;
    return (unsigned short)r;
}

// async 16B global -> LDS (per-lane global src, wave-uniform LDS base)
__device__ __forceinline__ void gload16(const void* g, void* l) {
    __builtin_amdgcn_global_load_lds(
        (const __attribute__((address_space(1))) unsigned*)g,
        (__attribute__((address_space(3))) unsigned*)l, 16, 0, 0);
}

// ---------------------------------------------------------------------------
// XLA:CPU vectorized f32 exp (Cephes, NO FMA — VERIFIED R10-R21).
// ---------------------------------------------------------------------------
__device__ __forceinline__ float xla_expf(float x) {
#pragma clang fp contract(off)
    float fx = floorf(x * 1.44269504088896341f + 0.5f);
    float tmp = fx * 0.693359375f;
    float z2  = fx * -2.12194440e-4f;
    float r = x - tmp;
    r = r - z2;
    float z = r * r;
    float y = 1.9875691500E-4f;
    y = y * r + 1.3981999507E-3f;
    y = y * r + 8.3334519073E-3f;
    y = y * r + 4.1665795894E-2f;
    y = y * r + 1.6666665459E-1f;
    y = y * r + 5.0000001201E-1f;
    y = y * z + r;
    y = y + 1.0f;
    int n = (int)fx;
    float p2n = __builtin_bit_cast(float, (unsigned)((n + 127) << 23));
    return y * p2n;
}

__device__ __forceinline__ float log_q32(float idf, float logr) {
    float l2 = (float)log((double)(idf + 2.0f));
    float l1 = (float)log((double)(idf + 1.0f));
    float q  = (l2 - l1) / logr;
    return (float)log((double)q);
}

// ---------------------------------------------------------------------------
// Kernel 1: prep = per-block dtype detect + tgt32 resolve + x->bf16 +
// threefry sample/corr (first 8192 threads). VERIFIED R21 (passed).
// ---------------------------------------------------------------------------
__global__ __launch_bounds__(256) void prep_kernel(
    const float* __restrict__ x, const int* __restrict__ tgt,
    const float* __restrict__ bias,
    unsigned short* __restrict__ Xb, int* __restrict__ tgt32,
    int* __restrict__ ids, float* __restrict__ corr,
    float logr, float logns)
{
    // ---- local dtype detect (OR of first 2048 odd words; int64 -> all 0) --
    __shared__ unsigned red[256];
    __shared__ unsigned is64s;
    {
        const unsigned* traw = (const unsigned*)tgt;
        unsigned acc = 0;
        for (int i = threadIdx.x; i < 2048; i += 256) acc |= traw[2 * i + 1];
        red[threadIdx.x] = acc;
        __syncthreads();
        for (int s = 128; s > 0; s >>= 1) {
            if ((int)threadIdx.x < s) red[threadIdx.x] |= red[threadIdx.x + s];
            __syncthreads();
        }
        if (threadIdx.x == 0) is64s = (red[0] == 0u) ? 1u : 0u;
        __syncthreads();
    }
    const unsigned is64 = is64s;

    int g = blockIdx.x * 256 + threadIdx.x;        // 0 .. 262143
    int row = g >> 4, chunk = g & 15;

    // ---- resolve target dtype -> int32 (one thread per row) ----
    if (chunk == 0) tgt32[row] = is64 ? tgt[2 * row] : tgt[row];

    // ---- x -> bf16 (thread per 8 elements) ----
    {
        const float4* src = (const float4*)(x + (size_t)row * DD + chunk * 8);
        float4 a = src[0], b = src[1];
        uint4 o;
        o.x = (unsigned)bf16r(a.x) | ((unsigned)bf16r(a.y) << 16);
        o.y = (unsigned)bf16r(a.z) | ((unsigned)bf16r(a.w) << 16);
        o.z = (unsigned)bf16r(b.x) | ((unsigned)bf16r(b.y) << 16);
        o.w = (unsigned)bf16r(b.z) | ((unsigned)bf16r(b.w) << 16);
        *(uint4*)(Xb + (size_t)row * DD + chunk * 8) = o;
    }

    // ---- sampling (first 8192 threads) ----
    if (g < NSAMP) {
        int i = g;
        const unsigned k0 = 0u, k1 = 1u;
        const unsigned k2 = 0x1BD11BDAu ^ k0 ^ k1;
        unsigned x0 = 0u + k0;
        unsigned x1 = (unsigned)i + k1;
#define TFR(r) { x0 += x1; x1 = rotl32(x1, (r)); x1 ^= x0; }
        TFR(13) TFR(15) TFR(26) TFR(6)   x0 += k1; x1 += k2 + 1u;
        TFR(17) TFR(29) TFR(16) TFR(24)  x0 += k2; x1 += k0 + 2u;
        TFR(13) TFR(15) TFR(26) TFR(6)   x0 += k0; x1 += k1 + 3u;
        TFR(17) TFR(29) TFR(16) TFR(24)  x0 += k1; x1 += k2 + 4u;
        TFR(13) TFR(15) TFR(26) TFR(6)   x0 += k2; x1 += k0 + 5u;
#undef TFR
        unsigned bits = x0 ^ x1;

        unsigned fb = (bits >> 9) | 0x3f800000u;
        float u = __builtin_bit_cast(float, fb) - 1.0f;
        float t = u * logr;
        float ef = xla_expf(t);
        int id = (int)floorf(ef) - 1;
        id = id < 0 ? 0 : (id > VV - 1 ? VV - 1 : id);

        float lp = log_q32((float)id, logr);
        ids[i]  = id;
        corr[i] = bias[id] - (logns + lp);
    }
}

// ---------------------------------------------------------------------------
// Kernel 2: gather candidate rows -> bf16 Wh (coalesced, 512 blocks).
// ---------------------------------------------------------------------------
__global__ __launch_bounds__(256) void gather_kernel(
    const float* __restrict__ emb, const int* __restrict__ ids,
    unsigned short* __restrict__ Wh)
{
    int g = blockIdx.x * 256 + threadIdx.x;    // 0 .. 131071
    int row   = g >> 4;
    int chunk = g & 15;
    const float4* src = (const float4*)(emb + (size_t)ids[row] * DD + chunk * 8);
    float4 a = src[0], b = src[1];
    uint4 o;
    o.x = (unsigned)bf16r(a.x) | ((unsigned)bf16r(a.y) << 16);
    o.y = (unsigned)bf16r(a.z) | ((unsigned)bf16r(a.w) << 16);
    o.z = (unsigned)bf16r(b.x) | ((unsigned)bf16r(b.y) << 16);
    o.w = (unsigned)bf16r(b.z) | ((unsigned)bf16r(b.w) << 16);
    *(uint4*)(Wh + (size_t)row * DD + chunk * 8) = o;
}

// ---------------------------------------------------------------------------
// Kernel 3: GEMM — slim-wave, high-occupancy variant.
// Wave = 32 rows x 32 cands, ONE MFMA chain, natural VGPR ~105 (< 128, no
// spill, unlike R21's fat 2-chain cap). Block = 64 rows, 4 waves (2x2);
// grid (256, 4) = 1024 blocks = 4 blocks/CU => 16 waves/CU. Cross-block
// phase-offset waves overlap MFMA/VALU/LDS/DMA (m114) — the overlap that
// barrier-locked 2-block residency (R16: gemm=53us serial-sum) lacked.
// Staging (linear LDS dest + inverse-swz src), swizzled reads, fixed-offset
// LSE exp(l-60), exact in-loop hit masking — all bit-identical to R16.
// ---------------------------------------------------------------------------
__device__ __forceinline__ int swz(int row, int slot) {
    return row * 256 + ((slot ^ (row & 15)) << 4);
}

__global__ __launch_bounds__(256, 4) void gemm_kernel(
    const unsigned short* __restrict__ Xb, const int* __restrict__ tgt32,
    const unsigned short* __restrict__ Wh,
    const int* __restrict__ ids, const float* __restrict__ corr,
    float* __restrict__ ps)
{
    __shared__ char lds[32768];   // 2 bufs x 16 KB

    const int tid  = threadIdx.x;
    const int lane = tid & 63;
    const int wid  = tid >> 6;
    const int wr   = wid >> 1, wc = wid & 1;
    const int half = lane >> 5, ln31 = lane & 31;
    const int m0   = blockIdx.x * 64;
    const int ty0  = blockIdx.y * (NT / 4);    // 32 tiles per y-quarter
    const int NTB  = NT / 4;

    // ---- A fragments: 32 rows x 128 k, bf16 direct loads (32 VGPRs) ----
    u16x8 ah[8];
    {
        const uint4* xr = (const uint4*)(Xb + (size_t)(m0 + wr * 32 + ln31) * DD);
        #pragma unroll
        for (int ks = 0; ks < 8; ks++)
            ah[ks] = __builtin_bit_cast(u16x8, xr[ks * 2 + half]);
    }

    // ---- targets for this lane's 16 C rows ----
    int t16[16];
    #pragma unroll
    for (int i = 0; i < 16; i++) {
        int grow = m0 + wr * 32 + (i & 3) + 8 * (i >> 2) + 4 * half;
        t16[i] = tgt32[grow];
    }

    float ss[16];
    #pragma unroll
    for (int i = 0; i < 16; i++) ss[i] = 0.f;

    // ---- staging geometry (rule #21: linear LDS dest + inverse-swz src) ----
    const int u    = lane & 15;
    const int rsub = lane >> 4;
    int srcoff[4], ldsrow[4];
    #pragma unroll
    for (int i2 = 0; i2 < 4; i2++) {
        int row = wid * 16 + i2 * 4 + rsub;
        srcoff[i2] = row * 256 + ((u ^ (row & 15)) << 4);
        ldsrow[i2] = (wid * 16 + i2 * 4) * 256;
    }
    const int brow = wc * 32 + ln31;

    // ---- prologue: DMA tile ty0 into buf 0 ----
    {
        const char* tb = (const char*)Wh + (size_t)(ty0 * 64) * 256;
        #pragma unroll
        for (int i2 = 0; i2 < 4; i2++)
            gload16(tb + srcoff[i2], lds + ldsrow[i2]);
    }
    __syncthreads();

    for (int t = 0; t < NTB; t++) {
        const int c = t & 1;
        if (t + 1 < NTB) {
            const char* tb = (const char*)Wh + (size_t)((ty0 + t + 1) * 64) * 256;
            char* db = lds + (c ^ 1) * 16384;
            #pragma unroll
            for (int i2 = 0; i2 < 4; i2++)
                gload16(tb + srcoff[i2], db + ldsrow[i2]);
        }

        const char* bh_base = lds + c * 16384;
        f32x16 h0;
        #pragma unroll
        for (int q = 0; q < 16; q++) h0[q] = 0.f;

        #pragma unroll
        for (int ks = 0; ks < 8; ks++) {
            int off = swz(brow, ks * 2 + half);
            bf16x8 bh = __builtin_bit_cast(bf16x8, *(const uint4*)(bh_base + off));
            bf16x8 a0 = __builtin_bit_cast(bf16x8, ah[ks]);
            h0 = __builtin_amdgcn_mfma_f32_32x32x16_bf16(a0, bh, h0, 0, 0, 0);
        }

        // epilogue: logit = C + corr - 60; exact hit mask; accumulate exp
        const int j = (ty0 + t) * 64 + wc * 32 + ln31;
        const float cc = corr[j] - 60.0f;
        const int idj = ids[j];
        #pragma unroll
        for (int i = 0; i < 16; i++) {
            float lt = h0[i] + cc;
            ss[i] += (idj == t16[i]) ? 0.0f : __expf(lt);
        }

        __syncthreads();
    }

    // ---- per-row reduce over 32 col-lanes, write per-wave partial ----
    #pragma unroll
    for (int i = 0; i < 16; i++) {
        float v = ss[i];
        v += __shfl_xor(v, 1);
        v += __shfl_xor(v, 2);
        v += __shfl_xor(v, 4);
        v += __shfl_xor(v, 8);
        v += __shfl_xor(v, 16);
        if (ln31 == 0) {
            int grow = m0 + wr * 32 + (i & 3) + 8 * (i >> 2) + 4 * half;
            ps[(size_t)grow * 8 + blockIdx.y * 2 + wc] = v;
        }
    }
}

// ---------------------------------------------------------------------------
// Kernel 4: finish = true logit (16 lanes/row, coalesced) + LSE combine.
// ---------------------------------------------------------------------------
__global__ __launch_bounds__(256) void finish_kernel(
    const float* __restrict__ x, const int* __restrict__ tgt32,
    const float* __restrict__ emb, const float* __restrict__ bias,
    const float* __restrict__ ps,
    float* __restrict__ out, float logr, float logns)
{
    const int gid = blockIdx.x * 256 + threadIdx.x;
    const int r   = gid >> 4;            // row
    const int l   = gid & 15;            // lane-in-row
    if (r >= BB) return;

    const int t = tgt32[r];

    const float4* xr = (const float4*)(x + (size_t)r * DD);
    const float4* wr = (const float4*)(emb + (size_t)t * DD);
    float4 xa = xr[l], xb = xr[l + 16];
    float4 wa = wr[l], wb = wr[l + 16];
    float d = xa.x*wa.x + xa.y*wa.y + xa.z*wa.z + xa.w*wa.w
            + xb.x*wb.x + xb.y*wb.y + xb.z*wb.z + xb.w*wb.w;
    d += __shfl_xor(d, 1);
    d += __shfl_xor(d, 2);
    d += __shfl_xor(d, 4);
    d += __shfl_xor(d, 8);

    if (l == 0) {
        float lp = log_q32((float)t, logr);
        float tl = d + bias[t] - (logns + lp);
        const float* p = ps + (size_t)r * 8;
        float S = ((p[0] + p[1]) + (p[2] + p[3])) + ((p[4] + p[5]) + (p[6] + p[7]));
        out[r] = logf(expf(tl - 60.0f) + S) + 60.0f - tl;
    }
}

// ---------------------------------------------------------------------------
extern "C" void kernel_launch(void* const* d_in, const int* in_sizes, int n_in,
                              void* d_out, int out_size, void* d_ws, size_t ws_size,
                              hipStream_t stream)
{
    const float* x    = (const float*)d_in[0];
    const int*   tgt  = (const int*)d_in[1];
    const float* emb  = (const float*)d_in[2];
    const float* bias = (const float*)d_in[3];
    float* out = (float*)d_out;

    char* w = (char*)d_ws;
    int*            ids   = (int*)(w + 0);                     //  32 KB
    float*          corr  = (float*)(w + 32768);               //  32 KB
    int*            tgt32 = (int*)(w + 65536);                 //  64 KB
    unsigned short* Xb    = (unsigned short*)(w + 131072);     //   4 MB
    unsigned short* Wh    = (unsigned short*)(w + 131072 + 4194304);  // 2 MB
    float*          ps    = (float*)(w + 131072 + 4194304 + 2097152); // 512 KB

    const float logr  = (float)log(1000001.0);
    const float logns = (float)log(8192.0);

    prep_kernel<<<dim3(BB * 16 / 256), dim3(256), 0, stream>>>(
        x, tgt, bias, Xb, tgt32, ids, corr, logr, logns);
    gather_kernel<<<dim3(NSAMP * 16 / 256), dim3(256), 0, stream>>>(
        emb, ids, Wh);
    gemm_kernel<<<dim3(BB / 64, 4), dim3(256), 0, stream>>>(
        Xb, tgt32, Wh, ids, corr, ps);
    finish_kernel<<<dim3(BB * 16 / 256), dim3(256), 0, stream>>>(
        x, tgt32, emb, bias, ps, out, logr, logns);
}

// Round 23
// 75.010 us; speedup vs baseline: 2.5867x; 1.0181x over previous
//
#include <hip/hip_runtime.h>
#include <math.h>

#define BB      16384   // batch rows
#define DD      128     // embedding dim
#define VV      1000000 // vocab
#define NSAMP   8192    // NUM_SAMPLED
#define NT      (NSAMP / 64)   // 128 N-tiles of 64 candidates

typedef __attribute__((ext_vector_type(8)))  unsigned short u16x8;
typedef __attribute__((ext_vector_type(8)))  __bf16         bf16x8;
typedef __attribute__((ext_vector_type(16))) float          f32x16;

__device__ __forceinline__ unsigned rotl32(unsigned x, unsigned r) {
    return (x << r) | (x >> (32u - r));
}

// RNE float -> bf16
__device__ __forceinline__ unsigned short bf16r(float v) {
    unsigned b = __builtin_bit_cast(unsigned, v);
    unsigned r = (b + 0x7fffu + ((b >> 16) & 1u)) >> 16;
    return (unsigned short)r;
}

// async 16B global -> LDS (per-lane global src, wave-uniform LDS base)
__device__ __forceinline__ void gload16(const void* g, void* l) {
    __builtin_amdgcn_global_load_lds(
        (const __attribute__((address_space(1))) unsigned*)g,
        (__attribute__((address_space(3))) unsigned*)l, 16, 0, 0);
}

// ---------------------------------------------------------------------------
// XLA:CPU vectorized f32 exp (Cephes, NO FMA — VERIFIED R10-R22).
// ---------------------------------------------------------------------------
__device__ __forceinline__ float xla_expf(float x) {
#pragma clang fp contract(off)
    float fx = floorf(x * 1.44269504088896341f + 0.5f);
    float tmp = fx * 0.693359375f;
    float z2  = fx * -2.12194440e-4f;
    float r = x - tmp;
    r = r - z2;
    float z = r * r;
    float y = 1.9875691500E-4f;
    y = y * r + 1.3981999507E-3f;
    y = y * r + 8.3334519073E-3f;
    y = y * r + 4.1665795894E-2f;
    y = y * r + 1.6666665459E-1f;
    y = y * r + 5.0000001201E-1f;
    y = y * z + r;
    y = y + 1.0f;
    int n = (int)fx;
    float p2n = __builtin_bit_cast(float, (unsigned)((n + 127) << 23));
    return y * p2n;
}

__device__ __forceinline__ float log_q32(float idf, float logr) {
    float l2 = (float)log((double)(idf + 2.0f));
    float l1 = (float)log((double)(idf + 1.0f));
    float q  = (l2 - l1) / logr;
    return (float)log((double)q);
}

// ---------------------------------------------------------------------------
// Kernel 1: prep = per-block dtype detect + tgt32 resolve + x->bf16 +
// threefry sample/corr (first 8192 threads). VERIFIED R21/R22.
// ---------------------------------------------------------------------------
__global__ __launch_bounds__(256) void prep_kernel(
    const float* __restrict__ x, const int* __restrict__ tgt,
    const float* __restrict__ bias,
    unsigned short* __restrict__ Xb, int* __restrict__ tgt32,
    int* __restrict__ ids, float* __restrict__ corr,
    float logr, float logns)
{
    __shared__ unsigned red[256];
    __shared__ unsigned is64s;
    {
        const unsigned* traw = (const unsigned*)tgt;
        unsigned acc = 0;
        for (int i = threadIdx.x; i < 2048; i += 256) acc |= traw[2 * i + 1];
        red[threadIdx.x] = acc;
        __syncthreads();
        for (int s = 128; s > 0; s >>= 1) {
            if ((int)threadIdx.x < s) red[threadIdx.x] |= red[threadIdx.x + s];
            __syncthreads();
        }
        if (threadIdx.x == 0) is64s = (red[0] == 0u) ? 1u : 0u;
        __syncthreads();
    }
    const unsigned is64 = is64s;

    int g = blockIdx.x * 256 + threadIdx.x;        // 0 .. 262143
    int row = g >> 4, chunk = g & 15;

    if (chunk == 0) tgt32[row] = is64 ? tgt[2 * row] : tgt[row];

    {
        const float4* src = (const float4*)(x + (size_t)row * DD + chunk * 8);
        float4 a = src[0], b = src[1];
        uint4 o;
        o.x = (unsigned)bf16r(a.x) | ((unsigned)bf16r(a.y) << 16);
        o.y = (unsigned)bf16r(a.z) | ((unsigned)bf16r(a.w) << 16);
        o.z = (unsigned)bf16r(b.x) | ((unsigned)bf16r(b.y) << 16);
        o.w = (unsigned)bf16r(b.z) | ((unsigned)bf16r(b.w) << 16);
        *(uint4*)(Xb + (size_t)row * DD + chunk * 8) = o;
    }

    if (g < NSAMP) {
        int i = g;
        const unsigned k0 = 0u, k1 = 1u;
        const unsigned k2 = 0x1BD11BDAu ^ k0 ^ k1;
        unsigned x0 = 0u + k0;
        unsigned x1 = (unsigned)i + k1;
#define TFR(r) { x0 += x1; x1 = rotl32(x1, (r)); x1 ^= x0; }
        TFR(13) TFR(15) TFR(26) TFR(6)   x0 += k1; x1 += k2 + 1u;
        TFR(17) TFR(29) TFR(16) TFR(24)  x0 += k2; x1 += k0 + 2u;
        TFR(13) TFR(15) TFR(26) TFR(6)   x0 += k0; x1 += k1 + 3u;
        TFR(17) TFR(29) TFR(16) TFR(24)  x0 += k1; x1 += k2 + 4u;
        TFR(13) TFR(15) TFR(26) TFR(6)   x0 += k2; x1 += k0 + 5u;
#undef TFR
        unsigned bits = x0 ^ x1;

        unsigned fb = (bits >> 9) | 0x3f800000u;
        float u = __builtin_bit_cast(float, fb) - 1.0f;
        float t = u * logr;
        float ef = xla_expf(t);
        int id = (int)floorf(ef) - 1;
        id = id < 0 ? 0 : (id > VV - 1 ? VV - 1 : id);

        float lp = log_q32((float)id, logr);
        ids[i]  = id;
        corr[i] = bias[id] - (logns + lp);
    }
}

// ---------------------------------------------------------------------------
// Kernel 2: gather candidate rows -> bf16 Wh (coalesced, 512 blocks).
// ---------------------------------------------------------------------------
__global__ __launch_bounds__(256) void gather_kernel(
    const float* __restrict__ emb, const int* __restrict__ ids,
    unsigned short* __restrict__ Wh)
{
    int g = blockIdx.x * 256 + threadIdx.x;    // 0 .. 131071
    int row   = g >> 4;
    int chunk = g & 15;
    const float4* src = (const float4*)(emb + (size_t)ids[row] * DD + chunk * 8);
    float4 a = src[0], b = src[1];
    uint4 o;
    o.x = (unsigned)bf16r(a.x) | ((unsigned)bf16r(a.y) << 16);
    o.y = (unsigned)bf16r(a.z) | ((unsigned)bf16r(a.w) << 16);
    o.z = (unsigned)bf16r(b.x) | ((unsigned)bf16r(b.y) << 16);
    o.w = (unsigned)bf16r(b.z) | ((unsigned)bf16r(b.w) << 16);
    *(uint4*)(Wh + (size_t)row * DD + chunk * 8) = o;
}

// ---------------------------------------------------------------------------
// Kernel 3: GEMM — R16 verified structure (fastest: 75.05 us) + PHASE
// STAGGER: block (bx,by) rotates its 32-tile loop start by
// ph = (bx*7 + by*13) & 31, breaking the cross-block convoy (R19 measured:
// pipes fully serialized = phase-aligned blocks queuing on the same pipe
// in lockstep). Only the ss accumulation ORDER changes per block (~1e-5
// noise); tile coverage, per-tile math, masking all bit-identical.
// ---------------------------------------------------------------------------
__device__ __forceinline__ int swz(int row, int slot) {
    return row * 256 + ((slot ^ (row & 15)) << 4);
}

__global__ __launch_bounds__(256, 2) void gemm_kernel(
    const unsigned short* __restrict__ Xb, const int* __restrict__ tgt32,
    const unsigned short* __restrict__ Wh,
    const int* __restrict__ ids, const float* __restrict__ corr,
    float* __restrict__ ps)
{
    __shared__ char lds[32768];   // 2 bufs x 16 KB

    const int tid  = threadIdx.x;
    const int lane = tid & 63;
    const int wid  = tid >> 6;
    const int wr   = wid >> 1, wc = wid & 1;
    const int half = lane >> 5, ln31 = lane & 31;
    const int m0   = blockIdx.x * 128;
    const int ty0  = blockIdx.y * (NT / 4);    // 32 tiles per y-quarter
    const int NTB  = NT / 4;
    const int ph   = (blockIdx.x * 7 + blockIdx.y * 13) & (NTB - 1);

    // ---- A fragments: two sets of 32 rows x 128 k, bf16 direct loads ----
    u16x8 ah[2][8];
    #pragma unroll
    for (int p = 0; p < 2; p++) {
        const uint4* xr = (const uint4*)(Xb + (size_t)(m0 + wr * 64 + p * 32 + ln31) * DD);
        #pragma unroll
        for (int ks = 0; ks < 8; ks++)
            ah[p][ks] = __builtin_bit_cast(u16x8, xr[ks * 2 + half]);
    }

    // ---- targets for this lane's 32 C rows (from pre-resolved tgt32) ----
    int t32[2][16];
    #pragma unroll
    for (int p = 0; p < 2; p++)
        #pragma unroll
        for (int i = 0; i < 16; i++) {
            int grow = m0 + wr * 64 + p * 32 + (i & 3) + 8 * (i >> 2) + 4 * half;
            t32[p][i] = tgt32[grow];
        }

    float ss[2][16];
    #pragma unroll
    for (int p = 0; p < 2; p++)
        #pragma unroll
        for (int i = 0; i < 16; i++) ss[p][i] = 0.f;

    // ---- staging geometry (rule #21: linear LDS dest + inverse-swz src) ----
    const int u    = lane & 15;
    const int rsub = lane >> 4;
    int srcoff[4], ldsrow[4];
    #pragma unroll
    for (int i2 = 0; i2 < 4; i2++) {
        int row = wid * 16 + i2 * 4 + rsub;
        srcoff[i2] = row * 256 + ((u ^ (row & 15)) << 4);
        ldsrow[i2] = (wid * 16 + i2 * 4) * 256;
    }
    const int brow = wc * 32 + ln31;

    // ---- prologue: DMA tile (ph) into buf 0 ----
    {
        const char* tb = (const char*)Wh + (size_t)((ty0 + ph) * 64) * 256;
        #pragma unroll
        for (int i2 = 0; i2 < 4; i2++)
            gload16(tb + srcoff[i2], lds + ldsrow[i2]);
    }
    __syncthreads();

    for (int tq = 0; tq < NTB; tq++) {
        const int c    = tq & 1;
        const int tcur = (tq + ph) & (NTB - 1);
        if (tq + 1 < NTB) {
            const int tnx = (tq + 1 + ph) & (NTB - 1);
            const char* tb = (const char*)Wh + (size_t)((ty0 + tnx) * 64) * 256;
            char* db = lds + (c ^ 1) * 16384;
            #pragma unroll
            for (int i2 = 0; i2 < 4; i2++)
                gload16(tb + srcoff[i2], db + ldsrow[i2]);
        }

        const char* bh_base = lds + c * 16384;
        f32x16 h0, h1;
        #pragma unroll
        for (int q = 0; q < 16; q++) { h0[q] = 0.f; h1[q] = 0.f; }

        #pragma unroll
        for (int ks = 0; ks < 8; ks++) {
            int off = swz(brow, ks * 2 + half);
            bf16x8 bh = __builtin_bit_cast(bf16x8, *(const uint4*)(bh_base + off));
            bf16x8 a0 = __builtin_bit_cast(bf16x8, ah[0][ks]);
            bf16x8 a1 = __builtin_bit_cast(bf16x8, ah[1][ks]);
            h0 = __builtin_amdgcn_mfma_f32_32x32x16_bf16(a0, bh, h0, 0, 0, 0);
            h1 = __builtin_amdgcn_mfma_f32_32x32x16_bf16(a1, bh, h1, 0, 0, 0);
        }

        // epilogue: logit = C + corr - 60; exact hit mask; accumulate exp
        const int j = (ty0 + tcur) * 64 + wc * 32 + ln31;
        const float cc = corr[j] - 60.0f;
        const int idj = ids[j];
        #pragma unroll
        for (int i = 0; i < 16; i++) {
            float l0 = h0[i] + cc;
            float l1 = h1[i] + cc;
            ss[0][i] += (idj == t32[0][i]) ? 0.0f : __expf(l0);
            ss[1][i] += (idj == t32[1][i]) ? 0.0f : __expf(l1);
        }

        __syncthreads();
    }

    // ---- per-row reduce over 32 col-lanes, write per-wave partial ----
    #pragma unroll
    for (int p = 0; p < 2; p++)
        #pragma unroll
        for (int i = 0; i < 16; i++) {
            float v = ss[p][i];
            v += __shfl_xor(v, 1);
            v += __shfl_xor(v, 2);
            v += __shfl_xor(v, 4);
            v += __shfl_xor(v, 8);
            v += __shfl_xor(v, 16);
            if (ln31 == 0) {
                int grow = m0 + wr * 64 + p * 32 + (i & 3) + 8 * (i >> 2) + 4 * half;
                ps[(size_t)grow * 8 + blockIdx.y * 2 + wc] = v;
            }
        }
}

// ---------------------------------------------------------------------------
// Kernel 4: finish = true logit (16 lanes/row, coalesced) + LSE combine.
// ---------------------------------------------------------------------------
__global__ __launch_bounds__(256) void finish_kernel(
    const float* __restrict__ x, const int* __restrict__ tgt32,
    const float* __restrict__ emb, const float* __restrict__ bias,
    const float* __restrict__ ps,
    float* __restrict__ out, float logr, float logns)
{
    const int gid = blockIdx.x * 256 + threadIdx.x;
    const int r   = gid >> 4;            // row
    const int l   = gid & 15;            // lane-in-row
    if (r >= BB) return;

    const int t = tgt32[r];

    const float4* xr = (const float4*)(x + (size_t)r * DD);
    const float4* wr = (const float4*)(emb + (size_t)t * DD);
    float4 xa = xr[l], xb = xr[l + 16];
    float4 wa = wr[l], wb = wr[l + 16];
    float d = xa.x*wa.x + xa.y*wa.y + xa.z*wa.z + xa.w*wa.w
            + xb.x*wb.x + xb.y*wb.y + xb.z*wb.z + xb.w*wb.w;
    d += __shfl_xor(d, 1);
    d += __shfl_xor(d, 2);
    d += __shfl_xor(d, 4);
    d += __shfl_xor(d, 8);

    if (l == 0) {
        float lp = log_q32((float)t, logr);
        float tl = d + bias[t] - (logns + lp);
        const float* p = ps + (size_t)r * 8;
        float S = ((p[0] + p[1]) + (p[2] + p[3])) + ((p[4] + p[5]) + (p[6] + p[7]));
        out[r] = logf(expf(tl - 60.0f) + S) + 60.0f - tl;
    }
}

// ---------------------------------------------------------------------------
extern "C" void kernel_launch(void* const* d_in, const int* in_sizes, int n_in,
                              void* d_out, int out_size, void* d_ws, size_t ws_size,
                              hipStream_t stream)
{
    const float* x    = (const float*)d_in[0];
    const int*   tgt  = (const int*)d_in[1];
    const float* emb  = (const float*)d_in[2];
    const float* bias = (const float*)d_in[3];
    float* out = (float*)d_out;

    char* w = (char*)d_ws;
    int*            ids   = (int*)(w + 0);                     //  32 KB
    float*          corr  = (float*)(w + 32768);               //  32 KB
    int*            tgt32 = (int*)(w + 65536);                 //  64 KB
    unsigned short* Xb    = (unsigned short*)(w + 131072);     //   4 MB
    unsigned short* Wh    = (unsigned short*)(w + 131072 + 4194304);  // 2 MB
    float*          ps    = (float*)(w + 131072 + 4194304 + 2097152); // 512 KB

    const float logr  = (float)log(1000001.0);
    const float logns = (float)log(8192.0);

    prep_kernel<<<dim3(BB * 16 / 256), dim3(256), 0, stream>>>(
        x, tgt, bias, Xb, tgt32, ids, corr, logr, logns);
    gather_kernel<<<dim3(NSAMP * 16 / 256), dim3(256), 0, stream>>>(
        emb, ids, Wh);
    gemm_kernel<<<dim3(BB / 128, 4), dim3(256), 0, stream>>>(
        Xb, tgt32, Wh, ids, corr, ps);
    finish_kernel<<<dim3(BB * 16 / 256), dim3(256), 0, stream>>>(
        x, tgt32, emb, bias, ps, out, logr, logns);
}